// Round 4
// baseline (79.163 us; speedup 1.0000x reference)
//
#include <hip/hip_runtime.h>

#define V 96
#define VV (V * V)
#define B_ 4
#define N_ 32
#define P_ 32
#define TILES (VV / 256)   // 36 pixel tiles per (b,n)

// One block = (b, n, 256-pixel tile). Edge data packed as 2 x float4 per
// edge in LDS (broadcast ds_read_b128 x2 per edge instead of 7 ds_read_b32).
__global__ __launch_bounds__(256) void mask_kernel(
    const float* __restrict__ poly,       // (B,N,P,2)
    const float* __restrict__ validity,   // (B,N)
    float* __restrict__ partial)          // (B*N, VV) per-polygon masks
{
    const int bn  = blockIdx.x / TILES;                  // b*N + n, block-uniform
    const int pix = (blockIdx.x % TILES) * 256 + threadIdx.x;

    if (validity[bn] < 0.5f) return;                     // block-uniform skip

    // e0 = {x0, y0, ex, ey}   e1 = {srq, y1, cI, sI}
    __shared__ float4 sE[P_][2];
    if (threadIdx.x < P_) {
        const int p  = threadIdx.x;
        const int pn = (p + 1) & (P_ - 1);
        const float* base = poly + (size_t)bn * (P_ * 2);
        float x0 = base[p * 2],  y0 = base[p * 2 + 1];
        float x1 = base[pn * 2], y1 = base[pn * 2 + 1];
        float ex = x1 - x0, ey = y1 - y0;
        float srq = __builtin_amdgcn_rcpf(ex * ex + ey * ey + 1e-8f);
        float sry = __builtin_amdgcn_rcpf(ey + 1e-8f);
        float sI  = ex * sry;
        float cI  = fmaf(-sI, y0, x0);    // inter_x = cI + sI*py
        sE[p][0] = make_float4(x0, y0, ex, ey);
        sE[p][1] = make_float4(srq, y1, cI, sI);
    }
    __syncthreads();

    // exact fp32 division to match numpy's grid (borderline y-comparisons)
    const int py_i = pix / V, px_i = pix - py_i * V;
    const float px = (float)px_i / 95.0f;
    const float py = (float)py_i / 95.0f;

    float mind2 = 1e30f;
    int   par   = 0;
    #pragma unroll
    for (int p = 0; p < P_; ++p) {
        const float4 e0 = sE[p][0];       // ds_read_b128, broadcast
        const float4 e1 = sE[p][1];

        float vx = px - e0.x, vy = py - e0.y;
        float t  = (vx * e0.z + vy * e0.w) * e1.x;
        t = fminf(fmaxf(t, 0.0f), 1.0f);                 // v_med3
        float dx = fmaf(-t, e0.z, vx), dy = fmaf(-t, e0.w, vy);
        float d2 = fmaf(dx, dx, dy * dy);
        mind2 = fminf(mind2, d2);

        bool c0 = (e0.y <= py);
        bool c1 = (e1.y <= py);                           // y1 exact vertex value
        float ix = fmaf(e1.w, py, e1.z);
        par ^= (int)((c0 != c1) & (ix > px));
    }
    float mind = sqrtf(mind2);
    float sdf  = par ? -mind : mind;
    // sigmoid(-100*sdf) = rcp(1 + exp2(100*log2e * sdf))
    float m = __builtin_amdgcn_rcpf(1.0f + __builtin_amdgcn_exp2f(sdf * 144.26950408889634f));

    partial[(size_t)bn * VV + pix] = m;
}

// One block = (b, y, d-quarter). Phase 1: threads<96 reduce max over valid n
// for one (b,y) pixel row into LDS. Phase 2: write 24 d-slices x 96 x.
__global__ __launch_bounds__(192) void expand_kernel(
    const float* __restrict__ partial,    // (B*N, VV)
    const float* __restrict__ validity,   // (B,N)
    const float* __restrict__ attr,       // (B,8)
    float4* __restrict__ out)             // (B,V,V,V)
{
    const int bid = blockIdx.x;           // B * V * 4 = 1536
    const int b   = bid / (V * 4);
    const int rem = bid - b * (V * 4);
    const int y   = rem >> 2;
    const int q   = rem & 3;
    const int t   = threadIdx.x;

    __shared__ float red[V];

    if (t < V) {
        const int x = t;
        float m = 0.0f;
        #pragma unroll
        for (int n = 0; n < N_; ++n) {
            if (validity[b * N_ + n] >= 0.5f) {   // uniform scalar branch
                m = fmaxf(m, partial[(size_t)(b * N_ + n) * VV + y * V + x]);
            }
        }
        red[x] = m;
    }
    __syncthreads();

    float a  = attr[b * 8];
    float nh = fminf(fmaxf(a, 0.0f), 1.0f);
    float hv = fminf(fmaxf(rintf(nh * (float)V), 1.0f), (float)V);  // half-even like numpy

    const float4* red4 = (const float4*)red;
    #pragma unroll
    for (int it = 0; it < 3; ++it) {
        const int idx = it * 192 + t;     // 0..575 = 24 d x 24 x4
        const int dl  = idx / 24;
        const int x4  = idx - dl * 24;
        const int d   = q * 24 + dl;
        const float keep = ((float)d < hv) ? 1.0f : 0.0f;
        float4 c = red4[x4];
        out[((size_t)(b * V + d) * V + y) * (V / 4) + x4] =
            make_float4(c.x * keep, c.y * keep, c.z * keep, c.w * keep);
    }
}

extern "C" void kernel_launch(void* const* d_in, const int* in_sizes, int n_in,
                              void* d_out, int out_size, void* d_ws, size_t ws_size,
                              hipStream_t stream) {
    const float* polygons = (const float*)d_in[0];   // (4,32,32,2)
    const float* attrs    = (const float*)d_in[1];   // (4,8)
    const float* validity = (const float*)d_in[2];   // (4,32)
    float* out     = (float*)d_out;                  // (4,96,96,96)
    float* partial = (float*)d_ws;                   // (128, 9216) floats

    mask_kernel<<<B_ * N_ * TILES, 256, 0, stream>>>(polygons, validity, partial);
    expand_kernel<<<B_ * V * 4, 192, 0, stream>>>(partial, validity, attrs, (float4*)out);
}

// Round 5
// 74.542 us; speedup vs baseline: 1.0620x; 1.0620x over previous
//
#include <hip/hip_runtime.h>

#define V 96
#define VV (V * V)
#define B_ 4
#define N_ 32
#define P_ 32
#define TPB 512                  // 8 waves
#define PXB 64                   // pixels per block (one per lane)
#define TILES_PER_B (VV / PXB)   // 144
#define WAVES (TPB / 64)         // 8
#define NPW (N_ / WAVES)         // 4 polygons per wave
#define DPW (V / WAVES)          // 12 depth slices per wave

// Single fused dispatch: per 64-pixel tile, 8 waves split the 32 polygons
// (4 each), LDS-atomicMax-reduce the soft masks, then write all 96 depth
// slices. No workspace, no inter-kernel gap.
__global__ __launch_bounds__(TPB) void fused_kernel(
    const float* __restrict__ poly,       // (B,N,P,2)
    const float* __restrict__ attr,       // (B,8)
    const float* __restrict__ validity,   // (B,N)
    float* __restrict__ out)              // (B,V,V,V)
{
    const int b    = blockIdx.x / TILES_PER_B;
    const int tile = blockIdx.x % TILES_PER_B;
    const int t    = threadIdx.x;
    const int wave = t >> 6;
    const int lane = t & 63;

    // e0 = {x0, y0, ex, ey}   e1 = {srq, y1, cI, sI}
    __shared__ float4 sE[N_][P_][2];          // 32 KB
    __shared__ unsigned int red[PXB];         // max-reduce, float bit pattern

    if (t < PXB) red[t] = 0u;

    // prep all 32*32 edges, 2 per thread
    for (int k = t; k < N_ * P_; k += TPB) {
        const int n = k >> 5, p = k & 31, pn = (p + 1) & 31;
        const float* base = poly + (size_t)(b * N_ + n) * (P_ * 2);
        float x0 = base[p * 2],  y0 = base[p * 2 + 1];
        float x1 = base[pn * 2], y1 = base[pn * 2 + 1];
        float ex = x1 - x0, ey = y1 - y0;
        float srq = __builtin_amdgcn_rcpf(ex * ex + ey * ey + 1e-8f);
        float sry = __builtin_amdgcn_rcpf(ey + 1e-8f);
        float sI  = ex * sry;
        float cI  = fmaf(-sI, y0, x0);        // inter_x = cI + sI*py
        sE[n][p][0] = make_float4(x0, y0, ex, ey);
        sE[n][p][1] = make_float4(srq, y1, cI, sI);
    }
    __syncthreads();

    // exact fp32 division to match numpy's grid (borderline y-comparisons)
    const int pix  = tile * PXB + lane;
    const int py_i = pix / V, px_i = pix - py_i * V;
    const float px = (float)px_i / 95.0f;
    const float py = (float)py_i / 95.0f;

    float best = 0.0f;
    #pragma unroll
    for (int i = 0; i < NPW; ++i) {
        const int n = wave * NPW + i;
        if (validity[b * N_ + n] < 0.5f) continue;   // wave-uniform skip

        float mind2 = 1e30f;
        int   par   = 0;
        #pragma unroll
        for (int p = 0; p < P_; ++p) {
            const float4 e0 = sE[n][p][0];    // broadcast ds_read_b128
            const float4 e1 = sE[n][p][1];

            float vx = px - e0.x, vy = py - e0.y;
            float tt = (vx * e0.z + vy * e0.w) * e1.x;
            tt = fminf(fmaxf(tt, 0.0f), 1.0f);
            float dx = fmaf(-tt, e0.z, vx), dy = fmaf(-tt, e0.w, vy);
            mind2 = fminf(mind2, fmaf(dx, dx, dy * dy));

            bool c0 = (e0.y <= py);
            bool c1 = (e1.y <= py);           // y1 exact vertex value
            float ix = fmaf(e1.w, py, e1.z);
            par ^= (int)((c0 != c1) & (ix > px));
        }
        float mind = sqrtf(mind2);
        float sdf  = par ? -mind : mind;
        // sigmoid(-100*sdf) = rcp(1 + exp2(100*log2e*sdf))
        float m = __builtin_amdgcn_rcpf(
            1.0f + __builtin_amdgcn_exp2f(sdf * 144.26950408889634f));
        best = fmaxf(best, m);
    }
    // best >= 0 -> uint bit-pattern order == float order
    atomicMax(&red[lane], __float_as_uint(best));
    __syncthreads();

    // write phase: wave w writes depth slices d = w*12 .. w*12+11
    const float a  = attr[b * 8];
    const float nh = fminf(fmaxf(a, 0.0f), 1.0f);
    const float hv = fminf(fmaxf(rintf(nh * (float)V), 1.0f), (float)V);  // half-even
    const float c  = __uint_as_float(red[lane]);
    float* obase = out + (size_t)b * V * VV + tile * PXB + lane;
    #pragma unroll
    for (int i = 0; i < DPW; ++i) {
        const int d = wave * DPW + i;
        const float keep = ((float)d < hv) ? 1.0f : 0.0f;
        obase[(size_t)d * VV] = c * keep;     // 64 contiguous floats per wave store
    }
}

extern "C" void kernel_launch(void* const* d_in, const int* in_sizes, int n_in,
                              void* d_out, int out_size, void* d_ws, size_t ws_size,
                              hipStream_t stream) {
    const float* polygons = (const float*)d_in[0];   // (4,32,32,2)
    const float* attrs    = (const float*)d_in[1];   // (4,8)
    const float* validity = (const float*)d_in[2];   // (4,32)
    float* out = (float*)d_out;                      // (4,96,96,96)

    fused_kernel<<<B_ * TILES_PER_B, TPB, 0, stream>>>(polygons, attrs, validity, out);
}